// Round 1
// baseline (91.936 us; speedup 1.0000x reference)
//
#include <hip/hip_runtime.h>
#include <hip/hip_bf16.h>

// Problem geometry (fixed by the reference):
//   B=8, S=256, T=64, H=128, N = B*H*H = 131072 pooled positions.
// Only channel 0 of the einsum survives -> only W[p,0] (p=0..3) is used.
// Normalization (min/max over t) is per pooled position, T=64 = one wave.

#define BB 8
#define SS 256
#define TT 64
#define HH 128

// Kernel 1: one 64-lane wave per pooled position (b,h,w).
//   c[t] = W0*in[b,2h,2w,t] + W1*in[b,2h,2w+1,t] + W2*in[b,2h+1,2w,t] + W3*in[b,2h+1,2w+1,t]
//   (p = 2r+c ordering from the reference unfold; W[p,0] at row-major offset p*6)
//   then min over t, subtract, max over t, divide; store [b,h,w,t] t-innermost.
__global__ __launch_bounds__(256) void pool_norm_kernel(
    const float* __restrict__ in, const float* __restrict__ W,
    float* __restrict__ pooled)
{
    const int gid  = blockIdx.x * blockDim.x + threadIdx.x;
    const int lane = gid & 63;          // t
    const int n    = gid >> 6;          // pooled position index
    const int w    = n & (HH - 1);
    const int h    = (n >> 7) & (HH - 1);
    const int b    = n >> 14;

    const float w0 = W[0];      // p=0 -> (r=0,c=0)
    const float w1 = W[6];      // p=1 -> (r=0,c=1)
    const float w2 = W[12];     // p=2 -> (r=1,c=0)
    const float w3 = W[18];     // p=3 -> (r=1,c=1)

    // input[b, row, col, t], t innermost; row stride = SS*TT, col stride = TT
    const size_t base = (((size_t)b * SS + 2 * h) * SS + 2 * w) * TT + lane;
    const float v = w0 * in[base]
                  + w1 * in[base + TT]
                  + w2 * in[base + (size_t)SS * TT]
                  + w3 * in[base + (size_t)SS * TT + TT];

    // min over the 64 lanes (= t axis)
    float m = v;
    #pragma unroll
    for (int off = 32; off >= 1; off >>= 1)
        m = fminf(m, __shfl_xor(m, off));

    const float s = v - m;

    // max over the 64 lanes of the shifted value
    float M = s;
    #pragma unroll
    for (int off = 32; off >= 1; off >>= 1)
        M = fmaxf(M, __shfl_xor(M, off));

    pooled[(size_t)n * TT + lane] = s / M;
}

// Kernel 2: bilinear upsample align_corners=True, 128 -> 256, writing the
// output in [b, s, s, t] layout (t innermost). One thread per output element.
__global__ __launch_bounds__(256) void upsample_kernel(
    const float* __restrict__ pooled, float* __restrict__ out)
{
    const size_t idx = (size_t)blockIdx.x * blockDim.x + threadIdx.x;
    // idx = ((b*256 + i)*256 + j)*64 + t
    const int t = (int)(idx & 63);
    const int j = (int)((idx >> 6) & 255);
    const int i = (int)((idx >> 14) & 255);
    const int b = (int)(idx >> 22);

    const float scale = 127.0f / 255.0f;   // (Hin-1)/(out-1), float32 as in ref

    const float pi = (float)i * scale;
    int   i0 = (int)pi;
    const float wi = pi - (float)i0;
    const int   i1 = min(i0 + 1, HH - 1);

    const float pj = (float)j * scale;
    int   j0 = (int)pj;
    const float wj = pj - (float)j0;
    const int   j1 = min(j0 + 1, HH - 1);

    const size_t pb = (size_t)b * (HH * HH * TT);
    const float v00 = pooled[pb + ((size_t)(i0 * HH + j0)) * TT + t];
    const float v01 = pooled[pb + ((size_t)(i0 * HH + j1)) * TT + t];
    const float v10 = pooled[pb + ((size_t)(i1 * HH + j0)) * TT + t];
    const float v11 = pooled[pb + ((size_t)(i1 * HH + j1)) * TT + t];

    // interpolate along H first, then W (matches reference order)
    const float a = v00 * (1.0f - wi) + v10 * wi;
    const float c = v01 * (1.0f - wi) + v11 * wi;
    out[idx] = a * (1.0f - wj) + c * wj;
}

extern "C" void kernel_launch(void* const* d_in, const int* in_sizes, int n_in,
                              void* d_out, int out_size, void* d_ws, size_t ws_size,
                              hipStream_t stream)
{
    const float* in = (const float*)d_in[0];   // [B,S,S,T] f32
    const float* W  = (const float*)d_in[1];   // [4,6] f32
    float* out      = (float*)d_out;           // [B*S*S, T] f32
    float* pooled   = (float*)d_ws;            // [B,H,H,T] f32 = 33.5 MB

    // Kernel 1: B*H*H waves, 4 waves (256 threads) per block
    {
        const int total_threads = BB * HH * HH * 64;   // 8.39M
        const int block = 256;
        const int grid  = total_threads / block;       // 32768
        pool_norm_kernel<<<grid, block, 0, stream>>>(in, W, pooled);
    }

    // Kernel 2: one thread per output element
    {
        const long long total = (long long)BB * SS * SS * TT;  // 33.55M
        const int block = 256;
        const long long grid = total / block;                  // 131072
        upsample_kernel<<<(int)grid, block, 0, stream>>>(pooled, out);
    }
}

// Round 3
// 48.925 us; speedup vs baseline: 1.8791x; 1.8791x over previous
//
#include <hip/hip_runtime.h>
#include <hip/hip_bf16.h>

// Geometry: B=8, S=256, T=64, H=128. Only einsum channel 0 survives -> 4-tap
// pool with W[0],W[6],W[12],W[18]; per-position min/max normalize over t=64;
// bilinear align_corners upsample 128->256.
//
// Fused: one block per (b, 32x32 output tile). Stage 1 computes the 18x18
// pooled positions the tile needs into LDS (bf16, 41.5 KB). Stage 2 blends
// from LDS and writes float4 stores.
//
// NOTE: plain stores, NOT __builtin_nontemporal_store — nt stores caused
// post-timing (graph-replay) divergence vs the 0xAA-poisoned d_out (stale
// dirty L2 lines vs streamed HBM writes). Round-1 plain stores were clean.

typedef float f32x4 __attribute__((ext_vector_type(4)));
typedef unsigned short u16x4 __attribute__((ext_vector_type(4)));

#define BB 8
#define SS 256
#define TT 64
#define HH 128
#define TILE 32
#define PL 18   // worst-case pooled span for 32 output rows (floor-diff 16 + i1 + round-up)

static __device__ __forceinline__ unsigned short f2bf(float f) {
    unsigned int u = __float_as_uint(f);
    u += 0x7FFFu + ((u >> 16) & 1u);   // RNE
    return (unsigned short)(u >> 16);
}
static __device__ __forceinline__ float bf2f(unsigned short h) {
    return __uint_as_float(((unsigned int)h) << 16);
}

__global__ __launch_bounds__(1024, 4) void fused_pool_up_kernel(
    const float* __restrict__ in, const float* __restrict__ W,
    float* __restrict__ out)
{
    __shared__ unsigned short plds[PL * PL * TT];   // bf16 pooled tile, 41.5 KB

    const int tile_j = blockIdx.x;
    const int tile_i = blockIdx.y;
    const int b      = blockIdx.z;
    const int tid    = threadIdx.x;

    const float scale = 127.0f / 255.0f;
    const int i_base = tile_i * TILE;
    const int j_base = tile_j * TILE;
    // same f32 expression as the per-pixel floor -> consistent, monotone
    const int p_i_lo = (int)((float)i_base * scale);
    const int p_j_lo = (int)((float)j_base * scale);

    const float w0 = W[0];    // p=0 -> (2h  , 2w  )
    const float w1 = W[6];    // p=1 -> (2h  , 2w+1)
    const float w2 = W[12];   // p=2 -> (2h+1, 2w  )
    const float w3 = W[18];   // p=3 -> (2h+1, 2w+1)

    // ---------- stage 1: pooled 18x18 -> LDS (bf16) ----------
    // 16 threads per pooled position (4 t-values each, float4 loads);
    // min/max over t = 4-step shfl_xor within the 16-lane group.
    const int grp = tid >> 4;          // position-group id
    const int t4  = (tid & 15) * 4;    // t offset

    for (int pp = grp; pp < PL * PL; pp += 64) {
        const int pr  = pp / PL;
        const int pc  = pp - pr * PL;
        const int gpr = min(p_i_lo + pr, HH - 1);
        const int gpc = min(p_j_lo + pc, HH - 1);

        const size_t base = (((size_t)b * SS + 2 * gpr) * SS + 2 * gpc) * TT + t4;
        const f32x4 va = *(const f32x4*)(in + base);
        const f32x4 vb = *(const f32x4*)(in + base + TT);
        const f32x4 vc = *(const f32x4*)(in + base + (size_t)SS * TT);
        const f32x4 vd = *(const f32x4*)(in + base + (size_t)SS * TT + TT);

        const f32x4 v = w0 * va + w1 * vb + w2 * vc + w3 * vd;

        float mn = fminf(fminf(v.x, v.y), fminf(v.z, v.w));
        #pragma unroll
        for (int off = 1; off < 16; off <<= 1)
            mn = fminf(mn, __shfl_xor(mn, off));

        const f32x4 s = v - mn;

        float mx = fmaxf(fmaxf(s.x, s.y), fmaxf(s.z, s.w));
        #pragma unroll
        for (int off = 1; off < 16; off <<= 1)
            mx = fmaxf(mx, __shfl_xor(mx, off));

        const float inv = 1.0f / mx;
        u16x4 h;
        h.x = f2bf(s.x * inv);
        h.y = f2bf(s.y * inv);
        h.z = f2bf(s.z * inv);
        h.w = f2bf(s.w * inv);
        *(u16x4*)(plds + (pr * PL + pc) * TT + t4) = h;
    }

    __syncthreads();

    // ---------- stage 2: bilinear blend -> out ----------
    const int t4i = tid & 15;          // float4 index along t
    const int jl  = (tid >> 4) & 31;   // local output col
    const int ih  = tid >> 9;          // 0/1, interleaved local rows

    const int   j   = j_base + jl;
    const float pjf = (float)j * scale;
    const int   j0  = (int)pjf;
    const float wj  = pjf - (float)j0;
    const int   j1  = min(j0 + 1, HH - 1);
    const int   j0l = j0 - p_j_lo;
    const int   j1l = j1 - p_j_lo;

    const u16x4* lds4 = (const u16x4*)plds;  // pooled position stride = 16 u16x4

    #pragma unroll
    for (int k = 0; k < 16; ++k) {
        const int   il  = 2 * k + ih;
        const int   i   = i_base + il;
        const float pif = (float)i * scale;
        const int   i0  = (int)pif;
        const float wi  = pif - (float)i0;
        const int   i1  = min(i0 + 1, HH - 1);
        const int   i0l = i0 - p_i_lo;
        const int   i1l = i1 - p_i_lo;

        const u16x4 h00 = lds4[(i0l * PL + j0l) * 16 + t4i];
        const u16x4 h01 = lds4[(i0l * PL + j1l) * 16 + t4i];
        const u16x4 h10 = lds4[(i1l * PL + j0l) * 16 + t4i];
        const u16x4 h11 = lds4[(i1l * PL + j1l) * 16 + t4i];

        f32x4 v00 = { bf2f(h00.x), bf2f(h00.y), bf2f(h00.z), bf2f(h00.w) };
        f32x4 v01 = { bf2f(h01.x), bf2f(h01.y), bf2f(h01.z), bf2f(h01.w) };
        f32x4 v10 = { bf2f(h10.x), bf2f(h10.y), bf2f(h10.z), bf2f(h10.w) };
        f32x4 v11 = { bf2f(h11.x), bf2f(h11.y), bf2f(h11.z), bf2f(h11.w) };

        // interpolate along H first, then W (reference order)
        const f32x4 a2 = v00 * (1.0f - wi) + v10 * wi;
        const f32x4 c2 = v01 * (1.0f - wi) + v11 * wi;
        const f32x4 r2 = a2 * (1.0f - wj) + c2 * wj;

        const size_t oidx = (((size_t)b * SS + i) * SS + j) * TT + 4 * t4i;
        *(f32x4*)(out + oidx) = r2;   // plain store (see NOTE above)
    }
}

extern "C" void kernel_launch(void* const* d_in, const int* in_sizes, int n_in,
                              void* d_out, int out_size, void* d_ws, size_t ws_size,
                              hipStream_t stream)
{
    const float* in = (const float*)d_in[0];   // [B,S,S,T] f32
    const float* W  = (const float*)d_in[1];   // [4,6] f32
    float* out      = (float*)d_out;           // [B*S*S, T] f32

    dim3 grid(SS / TILE, SS / TILE, BB);       // 8 x 8 x 8 = 512 blocks
    fused_pool_up_kernel<<<grid, 1024, 0, stream>>>(in, W, out);
}

// Round 5
// 48.910 us; speedup vs baseline: 1.8797x; 1.0003x over previous
//
#include <hip/hip_runtime.h>
#include <hip/hip_bf16.h>

// Geometry: B=8, S=256, T=64, H=128. Only einsum channel 0 survives -> 4-tap
// pool with W[0],W[6],W[12],W[18]; per-position min/max normalize over t=64;
// bilinear align_corners upsample 128->256.
//
// Fused: one block per (b, 32x32 output tile). Stage 1 computes the 18x18
// pooled positions the tile needs into LDS (bf16, 41.5 KB). Stage 2 blends
// from LDS and writes float4 stores.
//
// This is the round-3 configuration EXACTLY (passed end-to-end at 48.9 us,
// FETCH~84MB WRITE~134MB, 0 bank conflicts). Round 4's 512-thread/16x32
// variant was SLOWER (51.8 us replay) and hit the post-timing-divergence
// flake; round 2's nontemporal stores were likely innocent (round 4 failed
// with plain stores), but plain stores are kept — they passed and nt showed
// no measured upside.

typedef float f32x4 __attribute__((ext_vector_type(4)));
typedef unsigned short u16x4 __attribute__((ext_vector_type(4)));

#define BB 8
#define SS 256
#define TT 64
#define HH 128
#define TILE 32
#define PL 18   // worst-case pooled span for 32 output rows (floor-diff 16 + i1 + slack)

static __device__ __forceinline__ unsigned short f2bf(float f) {
    unsigned int u = __float_as_uint(f);
    u += 0x7FFFu + ((u >> 16) & 1u);   // RNE
    return (unsigned short)(u >> 16);
}
static __device__ __forceinline__ float bf2f(unsigned short h) {
    return __uint_as_float(((unsigned int)h) << 16);
}

__global__ __launch_bounds__(1024, 4) void fused_pool_up_kernel(
    const float* __restrict__ in, const float* __restrict__ W,
    float* __restrict__ out)
{
    __shared__ unsigned short plds[PL * PL * TT];   // bf16 pooled tile, 41.5 KB

    const int tile_j = blockIdx.x;
    const int tile_i = blockIdx.y;
    const int b      = blockIdx.z;
    const int tid    = threadIdx.x;

    const float scale = 127.0f / 255.0f;
    const int i_base = tile_i * TILE;
    const int j_base = tile_j * TILE;
    // same f32 expression as the per-pixel floor -> consistent, monotone
    const int p_i_lo = (int)((float)i_base * scale);
    const int p_j_lo = (int)((float)j_base * scale);

    const float w0 = W[0];    // p=0 -> (2h  , 2w  )
    const float w1 = W[6];    // p=1 -> (2h  , 2w+1)
    const float w2 = W[12];   // p=2 -> (2h+1, 2w  )
    const float w3 = W[18];   // p=3 -> (2h+1, 2w+1)

    // ---------- stage 1: pooled 18x18 -> LDS (bf16) ----------
    // 16 threads per pooled position (4 t-values each, float4 loads);
    // min/max over t = 4-step shfl_xor within the 16-lane group.
    const int grp = tid >> 4;          // position-group id
    const int t4  = (tid & 15) * 4;    // t offset

    for (int pp = grp; pp < PL * PL; pp += 64) {
        const int pr  = pp / PL;
        const int pc  = pp - pr * PL;
        const int gpr = min(p_i_lo + pr, HH - 1);
        const int gpc = min(p_j_lo + pc, HH - 1);

        const size_t base = (((size_t)b * SS + 2 * gpr) * SS + 2 * gpc) * TT + t4;
        const f32x4 va = *(const f32x4*)(in + base);
        const f32x4 vb = *(const f32x4*)(in + base + TT);
        const f32x4 vc = *(const f32x4*)(in + base + (size_t)SS * TT);
        const f32x4 vd = *(const f32x4*)(in + base + (size_t)SS * TT + TT);

        const f32x4 v = w0 * va + w1 * vb + w2 * vc + w3 * vd;

        float mn = fminf(fminf(v.x, v.y), fminf(v.z, v.w));
        #pragma unroll
        for (int off = 1; off < 16; off <<= 1)
            mn = fminf(mn, __shfl_xor(mn, off));

        const f32x4 s = v - mn;

        float mx = fmaxf(fmaxf(s.x, s.y), fmaxf(s.z, s.w));
        #pragma unroll
        for (int off = 1; off < 16; off <<= 1)
            mx = fmaxf(mx, __shfl_xor(mx, off));

        const float inv = 1.0f / mx;
        u16x4 h;
        h.x = f2bf(s.x * inv);
        h.y = f2bf(s.y * inv);
        h.z = f2bf(s.z * inv);
        h.w = f2bf(s.w * inv);
        *(u16x4*)(plds + (pr * PL + pc) * TT + t4) = h;
    }

    __syncthreads();

    // ---------- stage 2: bilinear blend -> out ----------
    const int t4i = tid & 15;          // float4 index along t
    const int jl  = (tid >> 4) & 31;   // local output col
    const int ih  = tid >> 9;          // 0/1, interleaved local rows

    const int   j   = j_base + jl;
    const float pjf = (float)j * scale;
    const int   j0  = (int)pjf;
    const float wj  = pjf - (float)j0;
    const int   j1  = min(j0 + 1, HH - 1);
    const int   j0l = j0 - p_j_lo;
    const int   j1l = j1 - p_j_lo;

    const u16x4* lds4 = (const u16x4*)plds;  // pooled position stride = 16 u16x4

    #pragma unroll
    for (int k = 0; k < 16; ++k) {
        const int   il  = 2 * k + ih;
        const int   i   = i_base + il;
        const float pif = (float)i * scale;
        const int   i0  = (int)pif;
        const float wi  = pif - (float)i0;
        const int   i1  = min(i0 + 1, HH - 1);
        const int   i0l = i0 - p_i_lo;
        const int   i1l = i1 - p_i_lo;

        const u16x4 h00 = lds4[(i0l * PL + j0l) * 16 + t4i];
        const u16x4 h01 = lds4[(i0l * PL + j1l) * 16 + t4i];
        const u16x4 h10 = lds4[(i1l * PL + j0l) * 16 + t4i];
        const u16x4 h11 = lds4[(i1l * PL + j1l) * 16 + t4i];

        f32x4 v00 = { bf2f(h00.x), bf2f(h00.y), bf2f(h00.z), bf2f(h00.w) };
        f32x4 v01 = { bf2f(h01.x), bf2f(h01.y), bf2f(h01.z), bf2f(h01.w) };
        f32x4 v10 = { bf2f(h10.x), bf2f(h10.y), bf2f(h10.z), bf2f(h10.w) };
        f32x4 v11 = { bf2f(h11.x), bf2f(h11.y), bf2f(h11.z), bf2f(h11.w) };

        // interpolate along H first, then W (reference order)
        const f32x4 a2 = v00 * (1.0f - wi) + v10 * wi;
        const f32x4 c2 = v01 * (1.0f - wi) + v11 * wi;
        const f32x4 r2 = a2 * (1.0f - wj) + c2 * wj;

        const size_t oidx = (((size_t)b * SS + i) * SS + j) * TT + 4 * t4i;
        *(f32x4*)(out + oidx) = r2;   // plain store (see NOTE above)
    }
}

extern "C" void kernel_launch(void* const* d_in, const int* in_sizes, int n_in,
                              void* d_out, int out_size, void* d_ws, size_t ws_size,
                              hipStream_t stream)
{
    const float* in = (const float*)d_in[0];   // [B,S,S,T] f32
    const float* W  = (const float*)d_in[1];   // [4,6] f32
    float* out      = (float*)d_out;           // [B*S*S, T] f32

    dim3 grid(SS / TILE, SS / TILE, BB);       // 8 x 8 x 8 = 512 blocks
    fused_pool_up_kernel<<<grid, 1024, 0, stream>>>(in, W, out);
}